// Round 3
// baseline (601.406 us; speedup 1.0000x reference)
//
#include <hip/hip_runtime.h>

#define NSEQ 16
#define HID 1024
#define HV (HID / 4)      // float4 per row = 256
#define TPB 256
#define MAXCHUNKS 128

typedef float f4 __attribute__((ext_vector_type(4)));

__device__ __forceinline__ bool lens_is64(const void* lens) {
    // Positive lengths < 2^31: little-endian int64 => word1 (high half of
    // lens[0]) == 0; int32 storage => word1 == lens[1] > 0.
    return ((const int*)lens)[1] == 0;
}

__device__ __forceinline__ long long seg_len(const void* lens, int i, bool is64) {
    return is64 ? ((const long long*)lens)[i] : (long long)((const int*)lens)[i];
}

// Fused: block b = s*chunks + c sums its token slab into ws[b][HID]; the
// last block of each seq (by atomic ticket) reduces the partials in fixed
// chunk order (bitwise-deterministic) and writes out.
__global__ void __launch_bounds__(TPB) seg_fused(
    const float* __restrict__ x, const void* __restrict__ lens,
    float* __restrict__ ws, int* __restrict__ cnt,
    float* __restrict__ out, int chunks) {
    int b = blockIdx.x;
    int s = b / chunks;
    int c = b - s * chunks;
    bool is64 = lens_is64(lens);
    long long off = 0;
    for (int i = 0; i < s; ++i) off += seg_len(lens, i, is64);
    long long len = seg_len(lens, s, is64);
    long long t0 = off + len * c / chunks;
    long long t1 = off + len * (c + 1) / chunks;
    int rows = (int)(t1 - t0);
    int tid = threadIdx.x;

    const f4* p = (const f4*)x + (size_t)t0 * HV + tid;
    f4 a0 = (f4)0.f, a1 = (f4)0.f, a2 = (f4)0.f, a3 = (f4)0.f;
    int r = 0;
    for (; r + 4 <= rows; r += 4) {
        // two-phase: all 4 dwordx4 loads issue before any use; nt = no
        // cache allocation for the 512 MB one-shot stream
        f4 v0 = __builtin_nontemporal_load(p + 0 * HV);
        f4 v1 = __builtin_nontemporal_load(p + 1 * HV);
        f4 v2 = __builtin_nontemporal_load(p + 2 * HV);
        f4 v3 = __builtin_nontemporal_load(p + 3 * HV);
        p += 4 * HV;
        a0 += v0;
        a1 += v1;
        a2 += v2;
        a3 += v3;
    }
    for (; r < rows; ++r) {
        a0 += __builtin_nontemporal_load(p);
        p += HV;
    }
    ((f4*)ws)[(size_t)b * HV + tid] = (a0 + a1) + (a2 + a3);

    // release: my partial visible at device scope before the ticket bump
    __threadfence();
    __syncthreads();
    __shared__ int isLast;
    if (tid == 0) {
        int ticket = __hip_atomic_fetch_add(&cnt[s], 1, __ATOMIC_ACQ_REL,
                                            __HIP_MEMORY_SCOPE_AGENT);
        isLast = (ticket == chunks - 1);
    }
    __syncthreads();
    if (!isLast) return;

    // acquire: invalidate local caches, then reduce in fixed order
    __threadfence();
    float inv = 1.0f / (float)len;
    const f4* wv = (const f4*)ws + (size_t)s * chunks * HV + tid;
    f4 acc = (f4)0.f;
    for (int k = 0; k < chunks; ++k) acc += wv[(size_t)k * HV];
    ((f4*)out)[(size_t)s * HV + tid] = acc * inv;
}

// Fallback if ws is too small: atomic accumulate of pre-scaled partials.
__global__ void __launch_bounds__(TPB) seg_atomic(
    const float* __restrict__ x, const void* __restrict__ lens,
    float* __restrict__ out, int chunks) {
    int b = blockIdx.x;
    int s = b / chunks;
    int c = b - s * chunks;
    bool is64 = lens_is64(lens);
    long long off = 0;
    for (int i = 0; i < s; ++i) off += seg_len(lens, i, is64);
    long long len = seg_len(lens, s, is64);
    long long t0 = off + len * c / chunks;
    long long t1 = off + len * (c + 1) / chunks;
    int tid = threadIdx.x;
    const f4* p = (const f4*)x + (size_t)t0 * HV + tid;
    f4 acc = (f4)0.f;
    for (long long t = t0; t < t1; ++t) {
        acc += *p;
        p += HV;
    }
    float inv = 1.0f / (float)len;
    float* o = out + (size_t)s * HID + tid * 4;
    atomicAdd(o + 0, acc.x * inv);
    atomicAdd(o + 1, acc.y * inv);
    atomicAdd(o + 2, acc.z * inv);
    atomicAdd(o + 3, acc.w * inv);
}

extern "C" void kernel_launch(void* const* d_in, const int* in_sizes, int n_in,
                              void* d_out, int out_size, void* d_ws, size_t ws_size,
                              hipStream_t stream) {
    const float* x = (const float*)d_in[0];
    const void* lens = d_in[1];
    float* out = (float*)d_out;

    size_t per_chunk = (size_t)NSEQ * HID * sizeof(float);  // 64 KiB per chunk layer
    long long avail = (long long)ws_size - 256;              // reserve counter space
    int chunks = avail > 0 ? (int)(avail / per_chunk) : 0;
    if (chunks > MAXCHUNKS) chunks = MAXCHUNKS;

    if (chunks >= 1) {
        int* cnt = (int*)((char*)d_ws + (size_t)chunks * per_chunk);
        hipMemsetAsync(cnt, 0, NSEQ * sizeof(int), stream);
        seg_fused<<<dim3(NSEQ * chunks), dim3(TPB), 0, stream>>>(
            x, lens, (float*)d_ws, cnt, out, chunks);
    } else {
        hipMemsetAsync(d_out, 0, (size_t)out_size * sizeof(float), stream);
        seg_atomic<<<dim3(NSEQ * 64), dim3(TPB), 0, stream>>>(x, lens, out, 64);
    }
}

// Round 4
// 117.421 us; speedup vs baseline: 5.1218x; 5.1218x over previous
//
#include <hip/hip_runtime.h>

#define NSEQ 16
#define HID 1024
#define HV (HID / 4)      // float4 per row = 256
#define TPB 256
#define TPB2 1024
#define MAXCHUNKS 128

typedef float f4 __attribute__((ext_vector_type(4)));

__device__ __forceinline__ bool lens_is64(const void* lens) {
    // Positive lengths < 2^31: little-endian int64 => word1 (high half of
    // lens[0]) == 0; int32 storage => word1 == lens[1] > 0.
    return ((const int*)lens)[1] == 0;
}

__device__ __forceinline__ long long seg_len(const void* lens, int i, bool is64) {
    return is64 ? ((const long long*)lens)[i] : (long long)((const int*)lens)[i];
}

// Stage 1: block b = s*chunks + c sums its token slab into ws[b][HID].
// Plain (allocating) loads: MALL random replacement retains ~C/S of the
// stream across replays (round-3 counter evidence: FETCH 266/537 MB).
__global__ void __launch_bounds__(TPB) seg_partial(
    const float* __restrict__ x, const void* __restrict__ lens,
    float* __restrict__ ws, int chunks) {
    int b = blockIdx.x;
    int s = b / chunks;
    int c = b - s * chunks;
    bool is64 = lens_is64(lens);
    long long off = 0;
    for (int i = 0; i < s; ++i) off += seg_len(lens, i, is64);
    long long len = seg_len(lens, s, is64);
    long long t0 = off + len * c / chunks;
    long long t1 = off + len * (c + 1) / chunks;
    int rows = (int)(t1 - t0);
    int tid = threadIdx.x;

    const f4* p = (const f4*)x + (size_t)t0 * HV + tid;
    f4 a0 = (f4)0.f, a1 = (f4)0.f, a2 = (f4)0.f, a3 = (f4)0.f;
    f4 a4 = (f4)0.f, a5 = (f4)0.f, a6 = (f4)0.f, a7 = (f4)0.f;
    int r = 0;
    for (; r + 8 <= rows; r += 8) {
        // two-phase: 8 dwordx4 loads issue back-to-back before any use
        f4 v0 = p[0 * HV];
        f4 v1 = p[1 * HV];
        f4 v2 = p[2 * HV];
        f4 v3 = p[3 * HV];
        f4 v4 = p[4 * HV];
        f4 v5 = p[5 * HV];
        f4 v6 = p[6 * HV];
        f4 v7 = p[7 * HV];
        p += 8 * HV;
        a0 += v0; a1 += v1; a2 += v2; a3 += v3;
        a4 += v4; a5 += v5; a6 += v6; a7 += v7;
    }
    for (; r < rows; ++r) {
        a0 += *p;
        p += HV;
    }
    f4 acc = ((a0 + a1) + (a2 + a3)) + ((a4 + a5) + (a6 + a7));
    ((f4*)ws)[(size_t)b * HV + tid] = acc;
}

// Stage 2: one 1024-thread block per seq; 4 chunk-groups in parallel,
// LDS tree-reduce, divide by len, write out.
__global__ void __launch_bounds__(TPB2) seg_finish(
    const float* __restrict__ ws, const void* __restrict__ lens,
    float* __restrict__ out, int chunks) {
    __shared__ f4 red[TPB2];
    int s = blockIdx.x;
    int tid = threadIdx.x;
    int col = tid & (HV - 1);   // 0..255 float4 column
    int q = tid >> 8;           // 0..3 chunk group
    bool is64 = lens_is64(lens);
    float inv = 1.0f / (float)seg_len(lens, s, is64);

    const f4* wv = (const f4*)ws + (size_t)s * chunks * HV + col;
    f4 acc = (f4)0.f;
    for (int c = q; c < chunks; c += 4) acc += wv[(size_t)c * HV];
    red[tid] = acc;
    __syncthreads();
    if (tid < 512) red[tid] += red[tid + 512];
    __syncthreads();
    if (tid < 256) {
        f4 r = (red[tid] + red[tid + 256]) * inv;
        ((f4*)out)[(size_t)s * HV + tid] = r;
    }
}

// Fallback if ws is too small: atomic accumulate of pre-scaled partials.
__global__ void __launch_bounds__(TPB) seg_atomic(
    const float* __restrict__ x, const void* __restrict__ lens,
    float* __restrict__ out, int chunks) {
    int b = blockIdx.x;
    int s = b / chunks;
    int c = b - s * chunks;
    bool is64 = lens_is64(lens);
    long long off = 0;
    for (int i = 0; i < s; ++i) off += seg_len(lens, i, is64);
    long long len = seg_len(lens, s, is64);
    long long t0 = off + len * c / chunks;
    long long t1 = off + len * (c + 1) / chunks;
    int tid = threadIdx.x;
    const f4* p = (const f4*)x + (size_t)t0 * HV + tid;
    f4 acc = (f4)0.f;
    for (long long t = t0; t < t1; ++t) {
        acc += *p;
        p += HV;
    }
    float inv = 1.0f / (float)len;
    float* o = out + (size_t)s * HID + tid * 4;
    atomicAdd(o + 0, acc.x * inv);
    atomicAdd(o + 1, acc.y * inv);
    atomicAdd(o + 2, acc.z * inv);
    atomicAdd(o + 3, acc.w * inv);
}

extern "C" void kernel_launch(void* const* d_in, const int* in_sizes, int n_in,
                              void* d_out, int out_size, void* d_ws, size_t ws_size,
                              hipStream_t stream) {
    const float* x = (const float*)d_in[0];
    const void* lens = d_in[1];
    float* out = (float*)d_out;

    size_t per_chunk = (size_t)NSEQ * HID * sizeof(float);  // 64 KiB per chunk layer
    int chunks = (int)(ws_size / per_chunk);
    if (chunks > MAXCHUNKS) chunks = MAXCHUNKS;

    if (chunks >= 1) {
        seg_partial<<<dim3(NSEQ * chunks), dim3(TPB), 0, stream>>>(
            x, lens, (float*)d_ws, chunks);
        seg_finish<<<dim3(NSEQ), dim3(TPB2), 0, stream>>>(
            (const float*)d_ws, lens, out, chunks);
    } else {
        hipMemsetAsync(d_out, 0, (size_t)out_size * sizeof(float), stream);
        seg_atomic<<<dim3(NSEQ * 64), dim3(TPB), 0, stream>>>(x, lens, out, 64);
    }
}

// Round 5
// 100.895 us; speedup vs baseline: 5.9607x; 1.1638x over previous
//
#include <hip/hip_runtime.h>

#define NSEQ 16
#define HID 1024
#define HV (HID / 4)      // float4 per row = 256
#define TPB 256
#define TPB2 1024
#define MAXCHUNKS 128

typedef float f4 __attribute__((ext_vector_type(4)));

__device__ __forceinline__ bool lens_is64(const void* lens) {
    // Positive lengths < 2^31: little-endian int64 => word1 (high half of
    // lens[0]) == 0; int32 storage => word1 == lens[1] > 0.
    return ((const int*)lens)[1] == 0;
}

__device__ __forceinline__ long long seg_len(const void* lens, int i, bool is64) {
    return is64 ? ((const long long*)lens)[i] : (long long)((const int*)lens)[i];
}

// Stage 1: block b = s*chunks + c sums its token slab into ws[b][HID].
// nt loads (round-2 A/B winner). 8 loads in flight, 4 accumulators:
// ~58 VGPR, and __launch_bounds__(256,8) pins <=64 VGPR so occupancy
// stays 8 waves/SIMD (32/CU). MLP*TLP is the stage-1 rate limiter.
__global__ void __launch_bounds__(TPB, 8) seg_partial(
    const float* __restrict__ x, const void* __restrict__ lens,
    float* __restrict__ ws, int chunks) {
    int b = blockIdx.x;
    int s = b / chunks;
    int c = b - s * chunks;
    bool is64 = lens_is64(lens);
    long long off = 0;
    for (int i = 0; i < s; ++i) off += seg_len(lens, i, is64);
    long long len = seg_len(lens, s, is64);
    long long t0 = off + len * c / chunks;
    long long t1 = off + len * (c + 1) / chunks;
    int rows = (int)(t1 - t0);
    int tid = threadIdx.x;

    const f4* p = (const f4*)x + (size_t)t0 * HV + tid;
    f4 a0 = (f4)0.f, a1 = (f4)0.f, a2 = (f4)0.f, a3 = (f4)0.f;
    int r = 0;
    for (; r + 8 <= rows; r += 8) {
        // two-phase: 8 dwordx4 nt loads issue back-to-back before any use
        f4 v0 = __builtin_nontemporal_load(p + 0 * HV);
        f4 v1 = __builtin_nontemporal_load(p + 1 * HV);
        f4 v2 = __builtin_nontemporal_load(p + 2 * HV);
        f4 v3 = __builtin_nontemporal_load(p + 3 * HV);
        f4 v4 = __builtin_nontemporal_load(p + 4 * HV);
        f4 v5 = __builtin_nontemporal_load(p + 5 * HV);
        f4 v6 = __builtin_nontemporal_load(p + 6 * HV);
        f4 v7 = __builtin_nontemporal_load(p + 7 * HV);
        p += 8 * HV;
        a0 += v0; a1 += v1; a2 += v2; a3 += v3;
        a0 += v4; a1 += v5; a2 += v6; a3 += v7;
    }
    for (; r < rows; ++r) {
        a0 += __builtin_nontemporal_load(p);
        p += HV;
    }
    f4 acc = (a0 + a1) + (a2 + a3);
    ((f4*)ws)[(size_t)b * HV + tid] = acc;
}

// Stage 2: one 1024-thread block per seq; 4 chunk-groups in parallel,
// LDS tree-reduce, divide by len, write out.
__global__ void __launch_bounds__(TPB2) seg_finish(
    const float* __restrict__ ws, const void* __restrict__ lens,
    float* __restrict__ out, int chunks) {
    __shared__ f4 red[TPB2];
    int s = blockIdx.x;
    int tid = threadIdx.x;
    int col = tid & (HV - 1);   // 0..255 float4 column
    int q = tid >> 8;           // 0..3 chunk group
    bool is64 = lens_is64(lens);
    float inv = 1.0f / (float)seg_len(lens, s, is64);

    const f4* wv = (const f4*)ws + (size_t)s * chunks * HV + col;
    f4 acc = (f4)0.f;
    for (int c = q; c < chunks; c += 4) acc += wv[(size_t)c * HV];
    red[tid] = acc;
    __syncthreads();
    if (tid < 512) red[tid] += red[tid + 512];
    __syncthreads();
    if (tid < 256) {
        f4 r = (red[tid] + red[tid + 256]) * inv;
        ((f4*)out)[(size_t)s * HV + tid] = r;
    }
}

// Fallback if ws is too small: atomic accumulate of pre-scaled partials.
__global__ void __launch_bounds__(TPB) seg_atomic(
    const float* __restrict__ x, const void* __restrict__ lens,
    float* __restrict__ out, int chunks) {
    int b = blockIdx.x;
    int s = b / chunks;
    int c = b - s * chunks;
    bool is64 = lens_is64(lens);
    long long off = 0;
    for (int i = 0; i < s; ++i) off += seg_len(lens, i, is64);
    long long len = seg_len(lens, s, is64);
    long long t0 = off + len * c / chunks;
    long long t1 = off + len * (c + 1) / chunks;
    int tid = threadIdx.x;
    const f4* p = (const f4*)x + (size_t)t0 * HV + tid;
    f4 acc = (f4)0.f;
    for (long long t = t0; t < t1; ++t) {
        acc += *p;
        p += HV;
    }
    float inv = 1.0f / (float)len;
    float* o = out + (size_t)s * HID + tid * 4;
    atomicAdd(o + 0, acc.x * inv);
    atomicAdd(o + 1, acc.y * inv);
    atomicAdd(o + 2, acc.z * inv);
    atomicAdd(o + 3, acc.w * inv);
}

extern "C" void kernel_launch(void* const* d_in, const int* in_sizes, int n_in,
                              void* d_out, int out_size, void* d_ws, size_t ws_size,
                              hipStream_t stream) {
    const float* x = (const float*)d_in[0];
    const void* lens = d_in[1];
    float* out = (float*)d_out;

    size_t per_chunk = (size_t)NSEQ * HID * sizeof(float);  // 64 KiB per chunk layer
    int chunks = (int)(ws_size / per_chunk);
    if (chunks > MAXCHUNKS) chunks = MAXCHUNKS;

    if (chunks >= 1) {
        seg_partial<<<dim3(NSEQ * chunks), dim3(TPB), 0, stream>>>(
            x, lens, (float*)d_ws, chunks);
        seg_finish<<<dim3(NSEQ), dim3(TPB2), 0, stream>>>(
            (const float*)d_ws, lens, out, chunks);
    } else {
        hipMemsetAsync(d_out, 0, (size_t)out_size * sizeof(float), stream);
        seg_atomic<<<dim3(NSEQ * 64), dim3(TPB), 0, stream>>>(x, lens, out, 64);
    }
}

// Round 6
// 93.844 us; speedup vs baseline: 6.4085x; 1.0751x over previous
//
#include <hip/hip_runtime.h>

#define NSEQ 16
#define HID 1024
#define HV (HID / 4)      // float4 per row = 256
#define TPB 256
#define TPB2 1024
#define MAXCHUNKS 128

typedef float f4 __attribute__((ext_vector_type(4)));

__device__ __forceinline__ bool lens_is64(const void* lens) {
    // Positive lengths < 2^31: little-endian int64 => word1 (high half of
    // lens[0]) == 0; int32 storage => word1 == lens[1] > 0.
    return ((const int*)lens)[1] == 0;
}

__device__ __forceinline__ long long seg_len(const void* lens, int i, bool is64) {
    return is64 ? ((const long long*)lens)[i] : (long long)((const int*)lens)[i];
}

// Stage 1 (unchanged from round 5 — at the ~5.9 TB/s read-path ceiling):
// block b = s*chunks + c sums its token slab into ws[b][HID]. nt loads,
// 8 in flight, 4 accumulators, pinned 8 waves/EU.
__global__ void __launch_bounds__(TPB, 8) seg_partial(
    const float* __restrict__ x, const void* __restrict__ lens,
    float* __restrict__ ws, int chunks) {
    int b = blockIdx.x;
    int s = b / chunks;
    int c = b - s * chunks;
    bool is64 = lens_is64(lens);
    long long off = 0;
    for (int i = 0; i < s; ++i) off += seg_len(lens, i, is64);
    long long len = seg_len(lens, s, is64);
    long long t0 = off + len * c / chunks;
    long long t1 = off + len * (c + 1) / chunks;
    int rows = (int)(t1 - t0);
    int tid = threadIdx.x;

    const f4* p = (const f4*)x + (size_t)t0 * HV + tid;
    f4 a0 = (f4)0.f, a1 = (f4)0.f, a2 = (f4)0.f, a3 = (f4)0.f;
    int r = 0;
    for (; r + 8 <= rows; r += 8) {
        // two-phase: 8 dwordx4 nt loads issue back-to-back before any use
        f4 v0 = __builtin_nontemporal_load(p + 0 * HV);
        f4 v1 = __builtin_nontemporal_load(p + 1 * HV);
        f4 v2 = __builtin_nontemporal_load(p + 2 * HV);
        f4 v3 = __builtin_nontemporal_load(p + 3 * HV);
        f4 v4 = __builtin_nontemporal_load(p + 4 * HV);
        f4 v5 = __builtin_nontemporal_load(p + 5 * HV);
        f4 v6 = __builtin_nontemporal_load(p + 6 * HV);
        f4 v7 = __builtin_nontemporal_load(p + 7 * HV);
        p += 8 * HV;
        a0 += v0; a1 += v1; a2 += v2; a3 += v3;
        a0 += v4; a1 += v5; a2 += v6; a3 += v7;
    }
    for (; r < rows; ++r) {
        a0 += __builtin_nontemporal_load(p);
        p += HV;
    }
    f4 acc = (a0 + a1) + (a2 + a3);
    ((f4*)ws)[(size_t)b * HV + tid] = acc;
}

// Stage 2: 64 blocks (4 per seq), each owns a 64-f4 channel slice.
// 16 chunk-groups per block accumulate in parallel, LDS tree-reduce in
// fixed order (deterministic), divide by len, write out.
__global__ void __launch_bounds__(TPB2) seg_finish(
    const float* __restrict__ ws, const void* __restrict__ lens,
    float* __restrict__ out, int chunks) {
    __shared__ f4 red[TPB2];
    int b = blockIdx.x;
    int s = b >> 2;
    int q = b & 3;                    // channel quarter
    int tid = threadIdx.x;
    int col = (q << 6) + (tid & 63);  // f4 column 0..255
    int grp = tid >> 6;               // chunk group 0..15
    bool is64 = lens_is64(lens);
    float inv = 1.0f / (float)seg_len(lens, s, is64);

    const f4* wv = (const f4*)ws + (size_t)s * chunks * HV + col;
    f4 acc = (f4)0.f;
    for (int c = grp; c < chunks; c += 16) acc += wv[(size_t)c * HV];
    red[tid] = acc;
    __syncthreads();
    if (tid < 512) red[tid] += red[tid + 512];
    __syncthreads();
    if (tid < 256) red[tid] += red[tid + 256];
    __syncthreads();
    if (tid < 128) red[tid] += red[tid + 128];
    __syncthreads();
    if (tid < 64) {
        f4 r = (red[tid] + red[tid + 64]) * inv;
        ((f4*)out)[(size_t)s * HV + col] = r;
    }
}

// Fallback if ws is too small: atomic accumulate of pre-scaled partials.
__global__ void __launch_bounds__(TPB) seg_atomic(
    const float* __restrict__ x, const void* __restrict__ lens,
    float* __restrict__ out, int chunks) {
    int b = blockIdx.x;
    int s = b / chunks;
    int c = b - s * chunks;
    bool is64 = lens_is64(lens);
    long long off = 0;
    for (int i = 0; i < s; ++i) off += seg_len(lens, i, is64);
    long long len = seg_len(lens, s, is64);
    long long t0 = off + len * c / chunks;
    long long t1 = off + len * (c + 1) / chunks;
    int tid = threadIdx.x;
    const f4* p = (const f4*)x + (size_t)t0 * HV + tid;
    f4 acc = (f4)0.f;
    for (long long t = t0; t < t1; ++t) {
        acc += *p;
        p += HV;
    }
    float inv = 1.0f / (float)len;
    float* o = out + (size_t)s * HID + tid * 4;
    atomicAdd(o + 0, acc.x * inv);
    atomicAdd(o + 1, acc.y * inv);
    atomicAdd(o + 2, acc.z * inv);
    atomicAdd(o + 3, acc.w * inv);
}

extern "C" void kernel_launch(void* const* d_in, const int* in_sizes, int n_in,
                              void* d_out, int out_size, void* d_ws, size_t ws_size,
                              hipStream_t stream) {
    const float* x = (const float*)d_in[0];
    const void* lens = d_in[1];
    float* out = (float*)d_out;

    size_t per_chunk = (size_t)NSEQ * HID * sizeof(float);  // 64 KiB per chunk layer
    int chunks = (int)(ws_size / per_chunk);
    if (chunks > MAXCHUNKS) chunks = MAXCHUNKS;

    if (chunks >= 1) {
        seg_partial<<<dim3(NSEQ * chunks), dim3(TPB), 0, stream>>>(
            x, lens, (float*)d_ws, chunks);
        seg_finish<<<dim3(NSEQ * 4), dim3(TPB2), 0, stream>>>(
            (const float*)d_ws, lens, out, chunks);
    } else {
        hipMemsetAsync(d_out, 0, (size_t)out_size * sizeof(float), stream);
        seg_atomic<<<dim3(NSEQ * 64), dim3(TPB), 0, stream>>>(x, lens, out, 64);
    }
}